// Round 12
// baseline (3013.618 us; speedup 1.0000x reference)
//
#include <hip/hip_runtime.h>
#include <cstdint>

#define JAX_PARTITIONABLE 1

#define OBS_LEN 20
#define PRED_LEN 30
#define NUM_MODES 6
#define BATCH 8192
#define H 256
#define MB (NUM_MODES * BATCH) /* 49152 */
#define KPAD 320               /* 40 x + 256 h + 24 zero pad */

typedef __attribute__((ext_vector_type(8))) short bf16x8;
typedef __attribute__((ext_vector_type(4))) float f32x4;

// ---------------- threefry2x32 (exact JAX semantics) ----------------
__host__ __device__ inline void tf2x32(uint32_t k0, uint32_t k1, uint32_t c0, uint32_t c1,
                                       uint32_t& o0, uint32_t& o1) {
  uint32_t ks0 = k0, ks1 = k1, ks2 = k0 ^ k1 ^ 0x1BD11BDAu;
  uint32_t x0 = c0 + ks0, x1 = c1 + ks1;
#define TF_R(x, r) (((x) << (r)) | ((x) >> (32 - (r))))
#define TF_RND(r)  { x0 += x1; x1 = TF_R(x1, r); x1 ^= x0; }
  TF_RND(13) TF_RND(15) TF_RND(26) TF_RND(6)   x0 += ks1; x1 += ks2 + 1u;
  TF_RND(17) TF_RND(29) TF_RND(16) TF_RND(24)  x0 += ks2; x1 += ks0 + 2u;
  TF_RND(13) TF_RND(15) TF_RND(26) TF_RND(6)   x0 += ks0; x1 += ks1 + 3u;
  TF_RND(17) TF_RND(29) TF_RND(16) TF_RND(24)  x0 += ks1; x1 += ks2 + 4u;
  TF_RND(13) TF_RND(15) TF_RND(26) TF_RND(6)   x0 += ks2; x1 += ks0 + 5u;
  o0 = x0; o1 = x1;
#undef TF_RND
#undef TF_R
}

__device__ inline void step_key(int m, int t, uint32_t& k0, uint32_t& k1) {
#if JAX_PARTITIONABLE
  tf2x32(0u, 42u, 0u, (uint32_t)(m * PRED_LEN + t), k0, k1);
#else
  int i = m * PRED_LEN + t;
  int n0 = 2 * i, n1 = 2 * i + 1;
  uint32_t a0, a1;
  if (n0 < 180) { tf2x32(0u, 42u, (uint32_t)n0, (uint32_t)(n0 + 180), a0, a1); k0 = a0; }
  else          { tf2x32(0u, 42u, (uint32_t)(n0 - 180), (uint32_t)n0, a0, a1); k0 = a1; }
  if (n1 < 180) { tf2x32(0u, 42u, (uint32_t)n1, (uint32_t)(n1 + 180), a0, a1); k1 = a0; }
  else          { tf2x32(0u, 42u, (uint32_t)(n1 - 180), (uint32_t)n1, a0, a1); k1 = a1; }
#endif
}

__device__ inline uint32_t mask_bits(uint32_t k0, uint32_t k1, uint32_t n) {
#if JAX_PARTITIONABLE
  uint32_t o0, o1;
  tf2x32(k0, k1, 0u, n, o0, o1);
  return o0 ^ o1;
#else
  const uint32_t HALF = (uint32_t)(BATCH * 40 / 2);
  uint32_t o0, o1;
  if (n < HALF) { tf2x32(k0, k1, n, n + HALF, o0, o1); return o0; }
  else          { tf2x32(k0, k1, n - HALF, n, o0, o1); return o1; }
#endif
}

__device__ __forceinline__ float sigf(float x) { return 1.0f / (1.0f + __expf(-x)); }
__device__ __forceinline__ float tanhfast(float x) {
  float e = __expf(-2.0f * fabsf(x));
  float t = (1.0f - e) / (1.0f + e);
  return x >= 0.f ? t : -t;
}
__device__ __forceinline__ ushort f2bf(float f) {
  uint32_t u = __float_as_uint(f);
  uint32_t r = (u + 0x7fffu + ((u >> 16) & 1u)) >> 16;
  return (ushort)r;
}
__device__ __forceinline__ float bf2f(uint32_t u) { return __uint_as_float(u << 16); }

// ---------------- masks: precompute all dropout keep-bits (bitwise-exact) ----------------
// masks[(m*30+t)*8192 + b] bit j = (uu < 0.75) with uu from threefry bits for element
// n = b*40+j under key step_key(m,t). Moves 59M threefry calls off the 30-step serial
// path into one parallel kernel.
__global__ __launch_bounds__(256) void k_masks(uint64_t* __restrict__ masks) {
  int idx = blockIdx.x * 256 + threadIdx.x;   // < NUM_MODES*PRED_LEN*BATCH
  if (idx >= NUM_MODES * PRED_LEN * BATCH) return;
  int b = idx & (BATCH - 1);
  int mt = idx >> 13;
  int m = mt / PRED_LEN, t = mt - m * PRED_LEN;
  uint32_t k0, k1;
  step_key(m, t, k0, k1);
  uint32_t nb = (uint32_t)(b * 40);
  uint64_t mk = 0;
  for (int j = 0; j < 40; j++) {
    uint32_t bits = mask_bits(k0, k1, nb + (uint32_t)j);
    float uu = __uint_as_float((bits >> 9) | 0x3f800000u) - 1.0f;
    if (uu < 0.75f) mk |= (1ull << j);
  }
  masks[idx] = mk;
}

// ---------------- prep: WTb[n'][320] bf16 (paired-col reorder), bias = b_ih + b_hh ----------------
// n' = cg*128 + nt*16 + col ; gate = nt&3 ; jg = nt>>2
// N_orig = gate*256 + cg*32 + col*2 + jg  (verified rounds 2/10/11)
__global__ __launch_bounds__(256) void k_prep(const float* __restrict__ Wih, const float* __restrict__ Whh,
                                              const float* __restrict__ bih, const float* __restrict__ bhh,
                                              ushort* __restrict__ WTb, float* __restrict__ bias) {
  int idx = blockIdx.x * 256 + threadIdx.x;
  if (idx < 1024 * KPAD) {
    int np = idx / KPAD, k = idx - np * KPAD;
    int cg = np >> 7, r = np & 127;
    int nt = r >> 4, col = r & 15;
    int N = (nt & 3) * 256 + cg * 32 + col * 2 + (nt >> 2);
    float v = (k < 40) ? Wih[N * 40 + k] : (k < 296 ? Whh[N * 256 + (k - 40)] : 0.f);
    WTb[idx] = f2bf(v);
  }
  if (idx < 1024) bias[idx] = bih[idx] + bhh[idx];
}

// ---------------- init: cst=c0 (fp32); A0 h-region = bf16(state_h); zero pads of A0,A1 ----------------
__global__ __launch_bounds__(256) void k_init(const float* __restrict__ state_h, const float* __restrict__ c0,
                                              float* __restrict__ cst, ushort* __restrict__ Ab0,
                                              ushort* __restrict__ Ab1) {
  int idx = blockIdx.x * 256 + threadIdx.x;   // < MB*64
  if (idx < MB * 64) {
    int row = idx >> 6;
    int j4 = (idx & 63) << 2;
    float4 cv = *(const float4*)(c0 + (size_t)idx * 4);
    *(float4*)(cst + (size_t)idx * 4) = cv;
    int b = row & (BATCH - 1);
    float4 hv = *(const float4*)(state_h + (size_t)b * H + j4);
    ushort4 hb = {f2bf(hv.x), f2bf(hv.y), f2bf(hv.z), f2bf(hv.w)};
    *(ushort4*)(Ab0 + (size_t)row * KPAD + 40 + j4) = hb;
  }
  if (idx < MB * 6) {
    int row = idx / 6, p4 = (idx - row * 6) << 2;
    ushort4 z = {0, 0, 0, 0};
    *(ushort4*)(Ab0 + (size_t)row * KPAD + 296 + p4) = z;
    *(ushort4*)(Ab1 + (size_t)row * KPAD + 296 + p4) = z;
  }
}

// ---------------- spatial embed + leaky relu + dropout -> bf16 x slice of A (t=0 only) ----------------
__global__ __launch_bounds__(256) void k_embed(const float* __restrict__ traj_rel, const float* __restrict__ rels,
                                               const float* __restrict__ Wse, const float* __restrict__ bse,
                                               const uint64_t* __restrict__ masks,
                                               ushort* __restrict__ Ax, int t) {
  __shared__ float sW[1600];
  __shared__ float sb[40];
  int tid = threadIdx.x;
  for (int i = tid; i < 1600; i += 256) sW[i] = Wse[i];
  if (tid < 40) sb[tid] = bse[tid];
  __syncthreads();
  int gid = blockIdx.x * 256 + tid;   // < MB
  int b = gid & (BATCH - 1);
  int m = gid >> 13;
  float win[40];
#pragma unroll
  for (int kk = 0; kk < OBS_LEN; kk++) {
    int st = t + kk;
    const float* p = (st < OBS_LEN)
        ? (traj_rel + (((size_t)st * BATCH + b) << 1))
        : (rels + (((size_t)(m * PRED_LEN + (st - OBS_LEN)) * BATCH + b) << 1));
    float2 w = *(const float2*)p;
    win[kk * 2] = w.x; win[kk * 2 + 1] = w.y;
  }
  uint64_t mk = masks[((size_t)(m * PRED_LEN + t) << 13) + b];
  ushort* orow = Ax + (size_t)gid * KPAD;
#pragma unroll
  for (int jo = 0; jo < 5; jo++) {
    uint32_t pk[4];
#pragma unroll
    for (int jp = 0; jp < 4; jp++) {
      ushort lo = 0, hi = 0;
#pragma unroll
      for (int ji = 0; ji < 2; ji++) {
        int j = jo * 8 + jp * 2 + ji;
        float a = sb[j];
#pragma unroll
        for (int p = 0; p < 40; p += 4) {
          float4 w = *(const float4*)&sW[j * 40 + p];
          a = fmaf(win[p + 3], w.w, fmaf(win[p + 2], w.z, fmaf(win[p + 1], w.y, fmaf(win[p], w.x, a))));
        }
        a = a > 0.f ? a : 0.01f * a;
        ushort r = ((mk >> j) & 1) ? f2bf(a * 1.3333333730697632f) : (ushort)0;
        if (ji == 0) lo = r; else hi = r;
      }
      pk[jp] = (uint32_t)lo | ((uint32_t)hi << 16);
    }
    uint4 v = {pk[0], pk[1], pk[2], pk[3]};
    *(uint4*)(orow + jo * 8) = v;
  }
}

// ---------------- MFMA gates GEMM (49152x320 @ 320x1024 bf16) + fused LSTM pointwise ----------------
// Round-11 verified best config: global_load_lds w=16 + pre-swizzled source (0 conflicts),
// 2-deep counted-vmcnt pipeline (no drain until last tile), 32KB LDS, paired-column epilogue.
__global__ __launch_bounds__(256, 4) void k_gates(const ushort* __restrict__ Ain, const ushort* __restrict__ WTb,
                                                  const float* __restrict__ bias, float* __restrict__ cst,
                                                  ushort* __restrict__ Anext) {
  __shared__ __align__(16) ushort lA[2][128][32];
  __shared__ __align__(16) ushort lB[2][128][32];
  int tid = threadIdx.x;
  int w = tid >> 6, lane = tid & 63;
  int row0 = blockIdx.x * 128;
  int cg = blockIdx.y;
  int fm = lane & 15, fq = lane >> 4;
  int srow = lane >> 2;
  int sg = (lane & 3) ^ ((lane >> 3) & 3);
  const ushort* gA0 = Ain + (size_t)(row0 + w * 32 + srow) * KPAD + sg * 8;
  const ushort* gA1 = Ain + (size_t)(row0 + w * 32 + 16 + srow) * KPAD + sg * 8;
  const ushort* gB0 = WTb + (size_t)(cg * 128 + w * 32 + srow) * KPAD + sg * 8;
  const ushort* gB1 = WTb + (size_t)(cg * 128 + w * 32 + 16 + srow) * KPAD + sg * 8;

#define STAGE(buf, kt) {                                                                      \
    __builtin_amdgcn_global_load_lds(                                                         \
        (const __attribute__((address_space(1))) uint32_t*)(gA0 + (kt) * 32),                 \
        (__attribute__((address_space(3))) uint32_t*)&lA[buf][w * 32][0], 16, 0, 0);          \
    __builtin_amdgcn_global_load_lds(                                                         \
        (const __attribute__((address_space(1))) uint32_t*)(gA1 + (kt) * 32),                 \
        (__attribute__((address_space(3))) uint32_t*)&lA[buf][w * 32 + 16][0], 16, 0, 0);     \
    __builtin_amdgcn_global_load_lds(                                                         \
        (const __attribute__((address_space(1))) uint32_t*)(gB0 + (kt) * 32),                 \
        (__attribute__((address_space(3))) uint32_t*)&lB[buf][w * 32][0], 16, 0, 0);          \
    __builtin_amdgcn_global_load_lds(                                                         \
        (const __attribute__((address_space(1))) uint32_t*)(gB1 + (kt) * 32),                 \
        (__attribute__((address_space(3))) uint32_t*)&lB[buf][w * 32 + 16][0], 16, 0, 0);     \
  }

  f32x4 zero = {0.f, 0.f, 0.f, 0.f};
  f32x4 acc[2][8];
#pragma unroll
  for (int i = 0; i < 2; i++)
#pragma unroll
    for (int j = 0; j < 8; j++) acc[i][j] = zero;

  STAGE(0, 0);
  STAGE(1, 1);

  int soff = (fq ^ ((fm >> 1) & 3)) * 8;
#pragma unroll
  for (int kt = 0; kt < 10; kt++) {
    int cur = kt & 1;
    if (kt < 9) { asm volatile("s_waitcnt vmcnt(4)" ::: "memory"); }
    else        { asm volatile("s_waitcnt vmcnt(0)" ::: "memory"); }
    __builtin_amdgcn_s_barrier();
    __builtin_amdgcn_sched_barrier(0);
    bf16x8 af[2], bfr[8];
#pragma unroll
    for (int rt = 0; rt < 2; rt++) af[rt] = *(const bf16x8*)&lA[cur][w * 32 + rt * 16 + fm][soff];
#pragma unroll
    for (int nt = 0; nt < 8; nt++) bfr[nt] = *(const bf16x8*)&lB[cur][nt * 16 + fm][soff];
#pragma unroll
    for (int rt = 0; rt < 2; rt++)
#pragma unroll
      for (int nt = 0; nt < 8; nt++)
        acc[rt][nt] = __builtin_amdgcn_mfma_f32_16x16x32_bf16(af[rt], bfr[nt], acc[rt][nt], 0, 0, 0);
    __builtin_amdgcn_sched_barrier(0);
    __builtin_amdgcn_s_barrier();
    if (kt < 8) STAGE(cur, kt + 2);
  }
#undef STAGE

  // epilogue: lane fm owns h-cols (2p, 2p+1), p = cg*16+fm. float2 cst, packed uint h store.
  int p = cg * 16 + fm;
  const float2* bias2 = (const float2*)bias;
  float2 bi = bias2[p], bff = bias2[128 + p], bgg = bias2[256 + p], boo = bias2[384 + p];
  float2* cst2 = (float2*)cst;
#pragma unroll
  for (int rt = 0; rt < 2; rt++) {
#pragma unroll
    for (int reg = 0; reg < 4; reg++) {
      int row = row0 + w * 32 + rt * 16 + fq * 4 + reg;
      float2 cv = cst2[(size_t)row * 128 + p];
      float gi0 = acc[rt][0][reg] + bi.x;
      float gf0 = acc[rt][1][reg] + bff.x;
      float gg0 = acc[rt][2][reg] + bgg.x;
      float go0 = acc[rt][3][reg] + boo.x;
      float gi1 = acc[rt][4][reg] + bi.y;
      float gf1 = acc[rt][5][reg] + bff.y;
      float gg1 = acc[rt][6][reg] + bgg.y;
      float go1 = acc[rt][7][reg] + boo.y;
      float c20 = sigf(gf0) * cv.x + sigf(gi0) * tanhfast(gg0);
      float c21 = sigf(gf1) * cv.y + sigf(gi1) * tanhfast(gg1);
      cst2[(size_t)row * 128 + p] = make_float2(c20, c21);
      float hn0 = sigf(go0) * tanhfast(c20);
      float hn1 = sigf(go1) * tanhfast(c21);
      uint32_t hp = (uint32_t)f2bf(hn0) | ((uint32_t)f2bf(hn1) << 16);
      *(uint32_t*)(Anext + (size_t)row * KPAD + 40 + 2 * p) = hp;
    }
  }
}

// ---------------- fused pred head + embed(t+1) ----------------
// Window loads hoisted before pred (latency overlap); dropout via precomputed mask table
// (threefry removed from the serial path); embed skipped at t==29 (te=30 never consumed).
__global__ __launch_bounds__(256) void k_predembed(const ushort* __restrict__ hsrc, const float* __restrict__ Wp,
                                                   const float* __restrict__ bp, float* __restrict__ rels,
                                                   const float* __restrict__ traj_rel,
                                                   const float* __restrict__ Wse, const float* __restrict__ bse,
                                                   const uint64_t* __restrict__ masks,
                                                   ushort* __restrict__ Ax, int t) {
  __shared__ float sW[1600];
  __shared__ float sb[40];
  int tid = threadIdx.x;
  for (int i = tid; i < 1600; i += 256) sW[i] = Wse[i];
  if (tid < 40) sb[tid] = bse[tid];
  __syncthreads();
  int wv = tid >> 6, lane = tid & 63;
  int grp = lane >> 3, lg = lane & 7;
  int row = blockIdx.x * 32 + wv * 8 + grp;
  int m = row / BATCH, b = row & (BATCH - 1);
  int te = t + 1;
  bool do_embed = (t < PRED_LEN - 1);

  // ---- prefetch window entries kk=0..18 (independent of this step's rel) ----
  float win[40];
  if (do_embed) {
#pragma unroll
    for (int kk = 0; kk < OBS_LEN - 1; kk++) {
      int st = te + kk;
      float2 w2;
      if (st < OBS_LEN) {
        w2 = *(const float2*)(traj_rel + (((size_t)st * BATCH + b) << 1));
      } else {
        w2 = *(const float2*)(rels + (((size_t)(m * PRED_LEN + (st - OBS_LEN)) * BATCH + b) << 1));
      }
      win[kk * 2] = w2.x; win[kk * 2 + 1] = w2.y;
    }
  }

  // ---- pred (identical math/order to verified k_pred) ----
  const ushort* hr = hsrc + (size_t)row * KPAD + 40 + lg * 32;
  const float* w0 = Wp + m * 512 + lg * 32;
  const float* w1 = w0 + 256;
  float s0 = 0.f, s1 = 0.f;
#pragma unroll
  for (int q = 0; q < 4; q++) {
    uint4 hv = *(const uint4*)(hr + q * 8);
    float h0 = bf2f(hv.x & 0xffffu), h1 = bf2f(hv.x >> 16);
    float h2 = bf2f(hv.y & 0xffffu), h3 = bf2f(hv.y >> 16);
    float h4 = bf2f(hv.z & 0xffffu), h5 = bf2f(hv.z >> 16);
    float h6 = bf2f(hv.w & 0xffffu), h7 = bf2f(hv.w >> 16);
    float4 wa0 = *(const float4*)(w0 + q * 8);
    float4 wa1 = *(const float4*)(w0 + q * 8 + 4);
    float4 wb0 = *(const float4*)(w1 + q * 8);
    float4 wb1 = *(const float4*)(w1 + q * 8 + 4);
    s0 += h0 * wa0.x + h1 * wa0.y + h2 * wa0.z + h3 * wa0.w
        + h4 * wa1.x + h5 * wa1.y + h6 * wa1.z + h7 * wa1.w;
    s1 += h0 * wb0.x + h1 * wb0.y + h2 * wb0.z + h3 * wb0.w
        + h4 * wb1.x + h5 * wb1.y + h6 * wb1.z + h7 * wb1.w;
  }
#pragma unroll
  for (int off = 1; off < 8; off <<= 1) {
    s0 += __shfl_xor(s0, off, 64);
    s1 += __shfl_xor(s1, off, 64);
  }
  float relx = s0 + bp[m * 2];
  float rely = s1 + bp[m * 2 + 1];
  if (lg == 0) {
    *(float2*)(rels + ((size_t)(m * PRED_LEN + t) * BATCH + b) * 2) = make_float2(relx, rely);
  }

  // ---- embed for step t+1 (identical math/order to verified kernel; mask from table) ----
  if (do_embed) {
    win[38] = relx;  // kk = 19 slot: st - OBS_LEN == t, the just-computed rel
    win[39] = rely;
    uint64_t mk = masks[((size_t)(m * PRED_LEN + te) << 13) + b];
    ushort* orow = Ax + (size_t)row * KPAD;
#pragma unroll
    for (int u = 0; u < 5; u++) {
      int j = lg * 5 + u;
      float a = sb[j];
#pragma unroll
      for (int p = 0; p < 40; p += 4) {
        float4 w = *(const float4*)&sW[j * 40 + p];
        a = fmaf(win[p + 3], w.w, fmaf(win[p + 2], w.z, fmaf(win[p + 1], w.y, fmaf(win[p], w.x, a))));
      }
      a = a > 0.f ? a : 0.01f * a;
      orow[j] = ((mk >> j) & 1) ? f2bf(a * 1.3333333730697632f) : (ushort)0;
    }
  }
}

// ---------------- transpose rels -> pred(B,M,T,2) + confidence net + softmax ----------------
__global__ __launch_bounds__(256) void k_transconf(const float* __restrict__ rels,
                                                   const float* __restrict__ W1, const float* __restrict__ b1,
                                                   const float* __restrict__ W2, const float* __restrict__ b2,
                                                   const float* __restrict__ wfc, const float* __restrict__ bfc,
                                                   float* __restrict__ out) {
  __shared__ float tile[32][361];
  __shared__ float sW1[3600];
  __shared__ float sW2[3600];
  __shared__ float sb1[60], sb2[60], swfc[60];
  __shared__ float sy1[192][61];
  __shared__ float slg[32][6];
  int tid = threadIdx.x;
  for (int i = tid; i < 3600; i += 256) { sW1[i] = W1[i]; sW2[i] = W2[i]; }
  if (tid < 60) { sb1[tid] = b1[tid]; sb2[tid] = b2[tid]; swfc[tid] = wfc[tid]; }
  int b0 = blockIdx.x * 32;
  for (int i = tid; i < 11520; i += 256) {
    int bl = i & 31, c = i >> 5;
    int mm = c / 60, r = c % 60;
    tile[bl][c] = rels[((size_t)((mm * PRED_LEN + (r >> 1)) * BATCH) + (b0 + bl)) * 2 + (r & 1)];
  }
  __syncthreads();
  for (int i = tid; i < 11520; i += 256) {
    int bl = i / 360, c = i % 360;
    out[(size_t)(b0 + bl) * 360 + c] = tile[bl][c];
  }
  if (tid < 192) {
    int bl = tid / 6, mm = tid - bl * 6;
    int xb = mm * 60;
    for (int q = 0; q < 60; q++) {
      float acl = sb1[q];
#pragma unroll
      for (int p = 0; p < 60; p++) acl = fmaf(tile[bl][xb + p], sW1[q * 60 + p], acl);
      sy1[tid][q] = fmaxf(acl, 0.f);
    }
    float logit = bfc[0];
    for (int q = 0; q < 60; q++) {
      float acl = sb2[q] + tile[bl][xb + q];
#pragma unroll
      for (int p = 0; p < 60; p++) acl = fmaf(sy1[tid][p], sW2[q * 60 + p], acl);
      logit = fmaf(fmaxf(acl, 0.f), swfc[q], logit);
    }
    slg[bl][mm] = logit;
  }
  __syncthreads();
  if (tid < 32) {
    float mx = slg[tid][0];
#pragma unroll
    for (int m = 1; m < 6; m++) mx = fmaxf(mx, slg[tid][m]);
    float e[6], s = 0.f;
#pragma unroll
    for (int m = 0; m < 6; m++) { e[m] = __expf(slg[tid][m] - mx); s += e[m]; }
    float inv = 1.0f / s;
    size_t base = (size_t)BATCH * 360 + (size_t)(b0 + tid) * 6;
#pragma unroll
    for (int m = 0; m < 6; m++) out[base + m] = e[m] * inv;
  }
}

// ---------------- host ----------------
extern "C" void kernel_launch(void* const* d_in, const int* in_sizes, int n_in,
                              void* d_out, int out_size, void* d_ws, size_t ws_size,
                              hipStream_t stream) {
  const float* traj_rel = (const float*)d_in[1];
  const float* state_h  = (const float*)d_in[2];
  const float* c0       = (const float*)d_in[3];
  const float* Wse      = (const float*)d_in[4];
  const float* bse      = (const float*)d_in[5];
  const float* Wih      = (const float*)d_in[6];
  const float* Whh      = (const float*)d_in[7];
  const float* bih      = (const float*)d_in[8];
  const float* bhh      = (const float*)d_in[9];
  const float* Wp       = (const float*)d_in[10];
  const float* bp       = (const float*)d_in[11];
  const float* W1       = (const float*)d_in[12];
  const float* b1       = (const float*)d_in[13];
  const float* W2       = (const float*)d_in[14];
  const float* b2       = (const float*)d_in[15];
  const float* wfc      = (const float*)d_in[16];
  const float* bfc      = (const float*)d_in[17];
  float* out = (float*)d_out;

  float* cst  = (float*)d_ws;                           // MB*H fp32
  float* rels = cst + (size_t)MB * H;                   // M*T*B*2 fp32
  float* bias = rels + (size_t)NUM_MODES * PRED_LEN * BATCH * 2;  // 1024 fp32
  ushort* WTb = (ushort*)(bias + 1024);                 // 1024*320 bf16
  ushort* Ab0 = WTb + (size_t)1024 * KPAD;              // MB*320 bf16
  ushort* Ab1 = Ab0 + (size_t)MB * KPAD;
  uint64_t* masks = (uint64_t*)(Ab1 + (size_t)MB * KPAD);  // M*T*B uint64 (11.8 MB)

  k_prep<<<1280, 256, 0, stream>>>(Wih, Whh, bih, bhh, WTb, bias);
  k_masks<<<5760, 256, 0, stream>>>(masks);
  k_init<<<12288, 256, 0, stream>>>(state_h, c0, cst, Ab0, Ab1);
  k_embed<<<192, 256, 0, stream>>>(traj_rel, rels, Wse, bse, masks, Ab0, 0);
  for (int t = 0; t < PRED_LEN; t++) {
    ushort* Acur  = (t & 1) ? Ab1 : Ab0;
    ushort* Anext = (t & 1) ? Ab0 : Ab1;
    k_gates<<<dim3(384, 8), 256, 0, stream>>>(Acur, WTb, bias, cst, Anext);
    // pred(t) from new h; embed(t+1) into the SAME buffer (x region) gates(t+1) reads.
    k_predembed<<<1536, 256, 0, stream>>>(Anext, Wp, bp, rels, traj_rel, Wse, bse, masks, Anext, t);
  }
  k_transconf<<<256, 256, 0, stream>>>(rels, W1, b1, W2, b2, wfc, bfc, out);
}

// Round 13
// 2875.226 us; speedup vs baseline: 1.0481x; 1.0481x over previous
//
#include <hip/hip_runtime.h>
#include <cstdint>

#define JAX_PARTITIONABLE 1

#define OBS_LEN 20
#define PRED_LEN 30
#define NUM_MODES 6
#define BATCH 8192
#define H 256
#define MB (NUM_MODES * BATCH) /* 49152 */
#define KPAD 320               /* 40 x + 256 h + 24 zero pad */

typedef __attribute__((ext_vector_type(8))) short bf16x8;
typedef __attribute__((ext_vector_type(4))) float f32x4;

// ---------------- threefry2x32 (exact JAX semantics) ----------------
__host__ __device__ inline void tf2x32(uint32_t k0, uint32_t k1, uint32_t c0, uint32_t c1,
                                       uint32_t& o0, uint32_t& o1) {
  uint32_t ks0 = k0, ks1 = k1, ks2 = k0 ^ k1 ^ 0x1BD11BDAu;
  uint32_t x0 = c0 + ks0, x1 = c1 + ks1;
#define TF_R(x, r) (((x) << (r)) | ((x) >> (32 - (r))))
#define TF_RND(r)  { x0 += x1; x1 = TF_R(x1, r); x1 ^= x0; }
  TF_RND(13) TF_RND(15) TF_RND(26) TF_RND(6)   x0 += ks1; x1 += ks2 + 1u;
  TF_RND(17) TF_RND(29) TF_RND(16) TF_RND(24)  x0 += ks2; x1 += ks0 + 2u;
  TF_RND(13) TF_RND(15) TF_RND(26) TF_RND(6)   x0 += ks0; x1 += ks1 + 3u;
  TF_RND(17) TF_RND(29) TF_RND(16) TF_RND(24)  x0 += ks1; x1 += ks2 + 4u;
  TF_RND(13) TF_RND(15) TF_RND(26) TF_RND(6)   x0 += ks2; x1 += ks0 + 5u;
  o0 = x0; o1 = x1;
#undef TF_RND
#undef TF_R
}

__device__ inline void step_key(int m, int t, uint32_t& k0, uint32_t& k1) {
#if JAX_PARTITIONABLE
  tf2x32(0u, 42u, 0u, (uint32_t)(m * PRED_LEN + t), k0, k1);
#else
  int i = m * PRED_LEN + t;
  int n0 = 2 * i, n1 = 2 * i + 1;
  uint32_t a0, a1;
  if (n0 < 180) { tf2x32(0u, 42u, (uint32_t)n0, (uint32_t)(n0 + 180), a0, a1); k0 = a0; }
  else          { tf2x32(0u, 42u, (uint32_t)(n0 - 180), (uint32_t)n0, a0, a1); k0 = a1; }
  if (n1 < 180) { tf2x32(0u, 42u, (uint32_t)n1, (uint32_t)(n1 + 180), a0, a1); k1 = a0; }
  else          { tf2x32(0u, 42u, (uint32_t)(n1 - 180), (uint32_t)n1, a0, a1); k1 = a1; }
#endif
}

__device__ inline uint32_t mask_bits(uint32_t k0, uint32_t k1, uint32_t n) {
#if JAX_PARTITIONABLE
  uint32_t o0, o1;
  tf2x32(k0, k1, 0u, n, o0, o1);
  return o0 ^ o1;
#else
  const uint32_t HALF = (uint32_t)(BATCH * 40 / 2);
  uint32_t o0, o1;
  if (n < HALF) { tf2x32(k0, k1, n, n + HALF, o0, o1); return o0; }
  else          { tf2x32(k0, k1, n - HALF, n, o0, o1); return o1; }
#endif
}

__device__ __forceinline__ float sigf(float x) { return 1.0f / (1.0f + __expf(-x)); }
__device__ __forceinline__ float tanhfast(float x) {
  float e = __expf(-2.0f * fabsf(x));
  float t = (1.0f - e) / (1.0f + e);
  return x >= 0.f ? t : -t;
}
__device__ __forceinline__ ushort f2bf(float f) {
  uint32_t u = __float_as_uint(f);
  uint32_t r = (u + 0x7fffu + ((u >> 16) & 1u)) >> 16;
  return (ushort)r;
}
__device__ __forceinline__ float bf2f(uint32_t u) { return __uint_as_float(u << 16); }

// ---------------- prep: WTb[n'][320] bf16 (paired-col reorder), bias = b_ih + b_hh ----------------
// n' = cg*128 + nt*16 + col ; gate = nt&3 ; jg = nt>>2
// N_orig = gate*256 + cg*32 + col*2 + jg  (verified rounds 2/10/11)
__global__ __launch_bounds__(256) void k_prep(const float* __restrict__ Wih, const float* __restrict__ Whh,
                                              const float* __restrict__ bih, const float* __restrict__ bhh,
                                              ushort* __restrict__ WTb, float* __restrict__ bias) {
  int idx = blockIdx.x * 256 + threadIdx.x;
  if (idx < 1024 * KPAD) {
    int np = idx / KPAD, k = idx - np * KPAD;
    int cg = np >> 7, r = np & 127;
    int nt = r >> 4, col = r & 15;
    int N = (nt & 3) * 256 + cg * 32 + col * 2 + (nt >> 2);
    float v = (k < 40) ? Wih[N * 40 + k] : (k < 296 ? Whh[N * 256 + (k - 40)] : 0.f);
    WTb[idx] = f2bf(v);
  }
  if (idx < 1024) bias[idx] = bih[idx] + bhh[idx];
}

// ---------------- init: cst=c0 (fp32); A0 h-region = bf16(state_h); zero pads of A0,A1 ----------------
__global__ __launch_bounds__(256) void k_init(const float* __restrict__ state_h, const float* __restrict__ c0,
                                              float* __restrict__ cst, ushort* __restrict__ Ab0,
                                              ushort* __restrict__ Ab1) {
  int idx = blockIdx.x * 256 + threadIdx.x;   // < MB*64
  if (idx < MB * 64) {
    int row = idx >> 6;
    int j4 = (idx & 63) << 2;
    float4 cv = *(const float4*)(c0 + (size_t)idx * 4);
    *(float4*)(cst + (size_t)idx * 4) = cv;
    int b = row & (BATCH - 1);
    float4 hv = *(const float4*)(state_h + (size_t)b * H + j4);
    ushort4 hb = {f2bf(hv.x), f2bf(hv.y), f2bf(hv.z), f2bf(hv.w)};
    *(ushort4*)(Ab0 + (size_t)row * KPAD + 40 + j4) = hb;
  }
  if (idx < MB * 6) {
    int row = idx / 6, p4 = (idx - row * 6) << 2;
    ushort4 z = {0, 0, 0, 0};
    *(ushort4*)(Ab0 + (size_t)row * KPAD + 296 + p4) = z;
    *(ushort4*)(Ab1 + (size_t)row * KPAD + 296 + p4) = z;
  }
}

// ---------------- spatial embed + leaky relu + dropout -> bf16 x slice of A (t=0 only) ----------------
__global__ __launch_bounds__(256) void k_embed(const float* __restrict__ traj_rel, const float* __restrict__ rels,
                                               const float* __restrict__ Wse, const float* __restrict__ bse,
                                               ushort* __restrict__ Ax, int t) {
  __shared__ float sW[1600];
  __shared__ float sb[40];
  int tid = threadIdx.x;
  for (int i = tid; i < 1600; i += 256) sW[i] = Wse[i];
  if (tid < 40) sb[tid] = bse[tid];
  __syncthreads();
  int gid = blockIdx.x * 256 + tid;   // < MB
  int b = gid & (BATCH - 1);
  int m = gid >> 13;
  float win[40];
#pragma unroll
  for (int kk = 0; kk < OBS_LEN; kk++) {
    int st = t + kk;
    const float* p = (st < OBS_LEN)
        ? (traj_rel + (((size_t)st * BATCH + b) << 1))
        : (rels + (((size_t)(m * PRED_LEN + (st - OBS_LEN)) * BATCH + b) << 1));
    float2 w = *(const float2*)p;
    win[kk * 2] = w.x; win[kk * 2 + 1] = w.y;
  }
  uint32_t k0, k1;
  step_key(m, t, k0, k1);
  uint32_t nb = (uint32_t)(b * 40);
  ushort* orow = Ax + (size_t)gid * KPAD;
#pragma unroll
  for (int jo = 0; jo < 5; jo++) {
    uint32_t pk[4];
#pragma unroll
    for (int jp = 0; jp < 4; jp++) {
      ushort lo = 0, hi = 0;
#pragma unroll
      for (int ji = 0; ji < 2; ji++) {
        int j = jo * 8 + jp * 2 + ji;
        float a = sb[j];
#pragma unroll
        for (int p = 0; p < 40; p += 4) {
          float4 w = *(const float4*)&sW[j * 40 + p];
          a = fmaf(win[p + 3], w.w, fmaf(win[p + 2], w.z, fmaf(win[p + 1], w.y, fmaf(win[p], w.x, a))));
        }
        a = a > 0.f ? a : 0.01f * a;
        uint32_t bits = mask_bits(k0, k1, nb + (uint32_t)j);
        float u = __uint_as_float((bits >> 9) | 0x3f800000u) - 1.0f;
        ushort r = (u < 0.75f) ? f2bf(a * 1.3333333730697632f) : (ushort)0;
        if (ji == 0) lo = r; else hi = r;
      }
      pk[jp] = (uint32_t)lo | ((uint32_t)hi << 16);
    }
    uint4 v = {pk[0], pk[1], pk[2], pk[3]};
    *(uint4*)(orow + jo * 8) = v;
  }
}

// ---------------- MFMA gates GEMM (49152x320 @ 320x1024 bf16) + fused LSTM pointwise ----------------
// Single-barrier pipeline: lA is WAVE-PRIVATE (wave w stages/reads only its own 32 rows;
// its ds_reads are lgkm-drained before the MFMAs, so re-staging after the MFMA block is
// race-free) -> 2 buffers, no barrier needed for lA. lB is block-shared -> 3 buffers:
// iter kt stages tile kt+2 into lB[(kt+2)%3], the buffer consumed at iter kt-1, which
// every wave finished reading before passing the top-of-kt barrier. One barrier/iter.
// vmcnt(4): at top of iter kt at most tile kt+1's 4 loads outstanding => tile kt complete.
// Bytes -> same MFMAs in same order as verified kernels -> bitwise-identical output.
__global__ __launch_bounds__(256, 4) void k_gates(const ushort* __restrict__ Ain, const ushort* __restrict__ WTb,
                                                  const float* __restrict__ bias, float* __restrict__ cst,
                                                  ushort* __restrict__ Anext) {
  __shared__ __align__(16) ushort lA[2][128][32];
  __shared__ __align__(16) ushort lB[3][128][32];
  int tid = threadIdx.x;
  int w = tid >> 6, lane = tid & 63;
  int row0 = blockIdx.x * 128;
  int cg = blockIdx.y;
  int fm = lane & 15, fq = lane >> 4;
  int srow = lane >> 2;
  int sg = (lane & 3) ^ ((lane >> 3) & 3);
  const ushort* gA0 = Ain + (size_t)(row0 + w * 32 + srow) * KPAD + sg * 8;
  const ushort* gA1 = Ain + (size_t)(row0 + w * 32 + 16 + srow) * KPAD + sg * 8;
  const ushort* gB0 = WTb + (size_t)(cg * 128 + w * 32 + srow) * KPAD + sg * 8;
  const ushort* gB1 = WTb + (size_t)(cg * 128 + w * 32 + 16 + srow) * KPAD + sg * 8;

#define STAGE(abuf, bbuf, kt) {                                                               \
    __builtin_amdgcn_global_load_lds(                                                         \
        (const __attribute__((address_space(1))) uint32_t*)(gA0 + (kt) * 32),                 \
        (__attribute__((address_space(3))) uint32_t*)&lA[abuf][w * 32][0], 16, 0, 0);         \
    __builtin_amdgcn_global_load_lds(                                                         \
        (const __attribute__((address_space(1))) uint32_t*)(gA1 + (kt) * 32),                 \
        (__attribute__((address_space(3))) uint32_t*)&lA[abuf][w * 32 + 16][0], 16, 0, 0);    \
    __builtin_amdgcn_global_load_lds(                                                         \
        (const __attribute__((address_space(1))) uint32_t*)(gB0 + (kt) * 32),                 \
        (__attribute__((address_space(3))) uint32_t*)&lB[bbuf][w * 32][0], 16, 0, 0);         \
    __builtin_amdgcn_global_load_lds(                                                         \
        (const __attribute__((address_space(1))) uint32_t*)(gB1 + (kt) * 32),                 \
        (__attribute__((address_space(3))) uint32_t*)&lB[bbuf][w * 32 + 16][0], 16, 0, 0);    \
  }

  f32x4 zero = {0.f, 0.f, 0.f, 0.f};
  f32x4 acc[2][8];
#pragma unroll
  for (int i = 0; i < 2; i++)
#pragma unroll
    for (int j = 0; j < 8; j++) acc[i][j] = zero;

  STAGE(0, 0, 0);
  STAGE(1, 1, 1);

  int soff = (fq ^ ((fm >> 1) & 3)) * 8;
#pragma unroll
  for (int kt = 0; kt < 10; kt++) {
    int ab = kt & 1;
    int bb = kt % 3;
    if (kt < 9) { asm volatile("s_waitcnt vmcnt(4)" ::: "memory"); }
    else        { asm volatile("s_waitcnt vmcnt(0)" ::: "memory"); }
    __builtin_amdgcn_s_barrier();
    __builtin_amdgcn_sched_barrier(0);
    bf16x8 af[2], bfr[8];
#pragma unroll
    for (int rt = 0; rt < 2; rt++) af[rt] = *(const bf16x8*)&lA[ab][w * 32 + rt * 16 + fm][soff];
#pragma unroll
    for (int nt = 0; nt < 8; nt++) bfr[nt] = *(const bf16x8*)&lB[bb][nt * 16 + fm][soff];
#pragma unroll
    for (int rt = 0; rt < 2; rt++)
#pragma unroll
      for (int nt = 0; nt < 8; nt++)
        acc[rt][nt] = __builtin_amdgcn_mfma_f32_16x16x32_bf16(af[rt], bfr[nt], acc[rt][nt], 0, 0, 0);
    __builtin_amdgcn_sched_barrier(0);
    if (kt < 8) STAGE(ab, (kt + 2) % 3, kt + 2);
  }
#undef STAGE

  // epilogue: lane fm owns h-cols (2p, 2p+1), p = cg*16+fm. float2 cst, packed uint h store.
  int p = cg * 16 + fm;
  const float2* bias2 = (const float2*)bias;
  float2 bi = bias2[p], bff = bias2[128 + p], bgg = bias2[256 + p], boo = bias2[384 + p];
  float2* cst2 = (float2*)cst;
#pragma unroll
  for (int rt = 0; rt < 2; rt++) {
#pragma unroll
    for (int reg = 0; reg < 4; reg++) {
      int row = row0 + w * 32 + rt * 16 + fq * 4 + reg;
      float2 cv = cst2[(size_t)row * 128 + p];
      float gi0 = acc[rt][0][reg] + bi.x;
      float gf0 = acc[rt][1][reg] + bff.x;
      float gg0 = acc[rt][2][reg] + bgg.x;
      float go0 = acc[rt][3][reg] + boo.x;
      float gi1 = acc[rt][4][reg] + bi.y;
      float gf1 = acc[rt][5][reg] + bff.y;
      float gg1 = acc[rt][6][reg] + bgg.y;
      float go1 = acc[rt][7][reg] + boo.y;
      float c20 = sigf(gf0) * cv.x + sigf(gi0) * tanhfast(gg0);
      float c21 = sigf(gf1) * cv.y + sigf(gi1) * tanhfast(gg1);
      cst2[(size_t)row * 128 + p] = make_float2(c20, c21);
      float hn0 = sigf(go0) * tanhfast(c20);
      float hn1 = sigf(go1) * tanhfast(c21);
      uint32_t hp = (uint32_t)f2bf(hn0) | ((uint32_t)f2bf(hn1) << 16);
      *(uint32_t*)(Anext + (size_t)row * KPAD + 40 + 2 * p) = hp;
    }
  }
}

// ---------------- fused pred head + embed(t+1) ----------------
// Window loads hoisted before pred (latency overlap); threefry inline (hides under load
// latency across the kernel); embed skipped at t==29 (te=30 never consumed; verified r12).
__global__ __launch_bounds__(256) void k_predembed(const ushort* __restrict__ hsrc, const float* __restrict__ Wp,
                                                   const float* __restrict__ bp, float* __restrict__ rels,
                                                   const float* __restrict__ traj_rel,
                                                   const float* __restrict__ Wse, const float* __restrict__ bse,
                                                   ushort* __restrict__ Ax, int t) {
  __shared__ float sW[1600];
  __shared__ float sb[40];
  int tid = threadIdx.x;
  for (int i = tid; i < 1600; i += 256) sW[i] = Wse[i];
  if (tid < 40) sb[tid] = bse[tid];
  __syncthreads();
  int wv = tid >> 6, lane = tid & 63;
  int grp = lane >> 3, lg = lane & 7;
  int row = blockIdx.x * 32 + wv * 8 + grp;
  int m = row / BATCH, b = row & (BATCH - 1);
  int te = t + 1;
  bool do_embed = (t < PRED_LEN - 1);

  // ---- prefetch window entries kk=0..18 (independent of this step's rel) ----
  float win[40];
  if (do_embed) {
#pragma unroll
    for (int kk = 0; kk < OBS_LEN - 1; kk++) {
      int st = te + kk;
      float2 w2;
      if (st < OBS_LEN) {
        w2 = *(const float2*)(traj_rel + (((size_t)st * BATCH + b) << 1));
      } else {
        w2 = *(const float2*)(rels + (((size_t)(m * PRED_LEN + (st - OBS_LEN)) * BATCH + b) << 1));
      }
      win[kk * 2] = w2.x; win[kk * 2 + 1] = w2.y;
    }
  }

  // ---- pred (identical math/order to verified k_pred) ----
  const ushort* hr = hsrc + (size_t)row * KPAD + 40 + lg * 32;
  const float* w0 = Wp + m * 512 + lg * 32;
  const float* w1 = w0 + 256;
  float s0 = 0.f, s1 = 0.f;
#pragma unroll
  for (int q = 0; q < 4; q++) {
    uint4 hv = *(const uint4*)(hr + q * 8);
    float h0 = bf2f(hv.x & 0xffffu), h1 = bf2f(hv.x >> 16);
    float h2 = bf2f(hv.y & 0xffffu), h3 = bf2f(hv.y >> 16);
    float h4 = bf2f(hv.z & 0xffffu), h5 = bf2f(hv.z >> 16);
    float h6 = bf2f(hv.w & 0xffffu), h7 = bf2f(hv.w >> 16);
    float4 wa0 = *(const float4*)(w0 + q * 8);
    float4 wa1 = *(const float4*)(w0 + q * 8 + 4);
    float4 wb0 = *(const float4*)(w1 + q * 8);
    float4 wb1 = *(const float4*)(w1 + q * 8 + 4);
    s0 += h0 * wa0.x + h1 * wa0.y + h2 * wa0.z + h3 * wa0.w
        + h4 * wa1.x + h5 * wa1.y + h6 * wa1.z + h7 * wa1.w;
    s1 += h0 * wb0.x + h1 * wb0.y + h2 * wb0.z + h3 * wb0.w
        + h4 * wb1.x + h5 * wb1.y + h6 * wb1.z + h7 * wb1.w;
  }
#pragma unroll
  for (int off = 1; off < 8; off <<= 1) {
    s0 += __shfl_xor(s0, off, 64);
    s1 += __shfl_xor(s1, off, 64);
  }
  float relx = s0 + bp[m * 2];
  float rely = s1 + bp[m * 2 + 1];
  if (lg == 0) {
    *(float2*)(rels + ((size_t)(m * PRED_LEN + t) * BATCH + b) * 2) = make_float2(relx, rely);
  }

  // ---- embed for step t+1 (identical math/order to verified kernel) ----
  if (do_embed) {
    win[38] = relx;  // kk = 19 slot: st - OBS_LEN == t, the just-computed rel
    win[39] = rely;
    uint32_t k0, k1;
    step_key(m, te, k0, k1);
    uint32_t nb = (uint32_t)(b * 40);
    ushort* orow = Ax + (size_t)row * KPAD;
#pragma unroll
    for (int u = 0; u < 5; u++) {
      int j = lg * 5 + u;
      float a = sb[j];
#pragma unroll
      for (int p = 0; p < 40; p += 4) {
        float4 w = *(const float4*)&sW[j * 40 + p];
        a = fmaf(win[p + 3], w.w, fmaf(win[p + 2], w.z, fmaf(win[p + 1], w.y, fmaf(win[p], w.x, a))));
      }
      a = a > 0.f ? a : 0.01f * a;
      uint32_t bits = mask_bits(k0, k1, nb + (uint32_t)j);
      float uu = __uint_as_float((bits >> 9) | 0x3f800000u) - 1.0f;
      orow[j] = (uu < 0.75f) ? f2bf(a * 1.3333333730697632f) : (ushort)0;
    }
  }
}

// ---------------- transpose rels -> pred(B,M,T,2) + confidence net + softmax ----------------
__global__ __launch_bounds__(256) void k_transconf(const float* __restrict__ rels,
                                                   const float* __restrict__ W1, const float* __restrict__ b1,
                                                   const float* __restrict__ W2, const float* __restrict__ b2,
                                                   const float* __restrict__ wfc, const float* __restrict__ bfc,
                                                   float* __restrict__ out) {
  __shared__ float tile[32][361];
  __shared__ float sW1[3600];
  __shared__ float sW2[3600];
  __shared__ float sb1[60], sb2[60], swfc[60];
  __shared__ float sy1[192][61];
  __shared__ float slg[32][6];
  int tid = threadIdx.x;
  for (int i = tid; i < 3600; i += 256) { sW1[i] = W1[i]; sW2[i] = W2[i]; }
  if (tid < 60) { sb1[tid] = b1[tid]; sb2[tid] = b2[tid]; swfc[tid] = wfc[tid]; }
  int b0 = blockIdx.x * 32;
  for (int i = tid; i < 11520; i += 256) {
    int bl = i & 31, c = i >> 5;
    int mm = c / 60, r = c % 60;
    tile[bl][c] = rels[((size_t)((mm * PRED_LEN + (r >> 1)) * BATCH) + (b0 + bl)) * 2 + (r & 1)];
  }
  __syncthreads();
  for (int i = tid; i < 11520; i += 256) {
    int bl = i / 360, c = i % 360;
    out[(size_t)(b0 + bl) * 360 + c] = tile[bl][c];
  }
  if (tid < 192) {
    int bl = tid / 6, mm = tid - bl * 6;
    int xb = mm * 60;
    for (int q = 0; q < 60; q++) {
      float acl = sb1[q];
#pragma unroll
      for (int p = 0; p < 60; p++) acl = fmaf(tile[bl][xb + p], sW1[q * 60 + p], acl);
      sy1[tid][q] = fmaxf(acl, 0.f);
    }
    float logit = bfc[0];
    for (int q = 0; q < 60; q++) {
      float acl = sb2[q] + tile[bl][xb + q];
#pragma unroll
      for (int p = 0; p < 60; p++) acl = fmaf(sy1[tid][p], sW2[q * 60 + p], acl);
      logit = fmaf(fmaxf(acl, 0.f), swfc[q], logit);
    }
    slg[bl][mm] = logit;
  }
  __syncthreads();
  if (tid < 32) {
    float mx = slg[tid][0];
#pragma unroll
    for (int m = 1; m < 6; m++) mx = fmaxf(mx, slg[tid][m]);
    float e[6], s = 0.f;
#pragma unroll
    for (int m = 0; m < 6; m++) { e[m] = __expf(slg[tid][m] - mx); s += e[m]; }
    float inv = 1.0f / s;
    size_t base = (size_t)BATCH * 360 + (size_t)(b0 + tid) * 6;
#pragma unroll
    for (int m = 0; m < 6; m++) out[base + m] = e[m] * inv;
  }
}

// ---------------- host ----------------
extern "C" void kernel_launch(void* const* d_in, const int* in_sizes, int n_in,
                              void* d_out, int out_size, void* d_ws, size_t ws_size,
                              hipStream_t stream) {
  const float* traj_rel = (const float*)d_in[1];
  const float* state_h  = (const float*)d_in[2];
  const float* c0       = (const float*)d_in[3];
  const float* Wse      = (const float*)d_in[4];
  const float* bse      = (const float*)d_in[5];
  const float* Wih      = (const float*)d_in[6];
  const float* Whh      = (const float*)d_in[7];
  const float* bih      = (const float*)d_in[8];
  const float* bhh      = (const float*)d_in[9];
  const float* Wp       = (const float*)d_in[10];
  const float* bp       = (const float*)d_in[11];
  const float* W1       = (const float*)d_in[12];
  const float* b1       = (const float*)d_in[13];
  const float* W2       = (const float*)d_in[14];
  const float* b2       = (const float*)d_in[15];
  const float* wfc      = (const float*)d_in[16];
  const float* bfc      = (const float*)d_in[17];
  float* out = (float*)d_out;

  float* cst  = (float*)d_ws;                           // MB*H fp32
  float* rels = cst + (size_t)MB * H;                   // M*T*B*2 fp32
  float* bias = rels + (size_t)NUM_MODES * PRED_LEN * BATCH * 2;  // 1024 fp32
  ushort* WTb = (ushort*)(bias + 1024);                 // 1024*320 bf16
  ushort* Ab0 = WTb + (size_t)1024 * KPAD;              // MB*320 bf16
  ushort* Ab1 = Ab0 + (size_t)MB * KPAD;

  k_prep<<<1280, 256, 0, stream>>>(Wih, Whh, bih, bhh, WTb, bias);
  k_init<<<12288, 256, 0, stream>>>(state_h, c0, cst, Ab0, Ab1);
  k_embed<<<192, 256, 0, stream>>>(traj_rel, rels, Wse, bse, Ab0, 0);
  for (int t = 0; t < PRED_LEN; t++) {
    ushort* Acur  = (t & 1) ? Ab1 : Ab0;
    ushort* Anext = (t & 1) ? Ab0 : Ab1;
    k_gates<<<dim3(384, 8), 256, 0, stream>>>(Acur, WTb, bias, cst, Anext);
    // pred(t) from new h; embed(t+1) into the SAME buffer (x region) gates(t+1) reads.
    k_predembed<<<1536, 256, 0, stream>>>(Anext, Wp, bp, rels, traj_rel, Wse, bse, Anext, t);
  }
  k_transconf<<<256, 256, 0, stream>>>(rels, W1, b1, W2, b2, wfc, bfc, out);
}